// Round 1
// baseline (466.442 us; speedup 1.0000x reference)
//
#include <hip/hip_runtime.h>

#define DEVI __device__ __forceinline__

typedef unsigned short u16;
typedef unsigned int   u32;
typedef u16  u16x8 __attribute__((ext_vector_type(8)));
typedef u16  u16x4 __attribute__((ext_vector_type(4)));
typedef short bf16x8 __attribute__((ext_vector_type(8)));
typedef float f32x4 __attribute__((ext_vector_type(4)));

static constexpr int BB = 16, NN = 4096, GG = 1024;
static constexpr int D1 = 128, D2 = 256, CIN = 384, CH = 256;

DEVI float bf2f(u16 h) { u32 u = ((u32)h) << 16; float f; __builtin_memcpy(&f, &u, 4); return f; }
DEVI u16 f2bf(float f) {
    u32 u; __builtin_memcpy(&u, &f, 4);
    u32 r = (u + 0x7fffu + ((u >> 16) & 1u)) >> 16;
    return (u16)r;
}

DEVI void gload16(const void* g, void* l) {
    __builtin_amdgcn_global_load_lds((const __attribute__((address_space(1))) void*)g,
                                     (__attribute__((address_space(3))) void*)l, 16, 0, 0);
}

// ---------------- weight conversion fp32 -> bf16 ----------------
__global__ void k_convw(const float* __restrict__ W1, const float* __restrict__ W2,
                        u16* __restrict__ W1b, u16* __restrict__ W2b) {
    int i = blockIdx.x * 256 + threadIdx.x;
    if (i < CH * CIN) W1b[i] = f2bf(W1[i]);
    int j = i - CH * CIN;
    if (j >= 0 && j < CH * CH) W2b[j] = f2bf(W2[j]);
}

// ---------------- feature2 transpose: [B][256][1024] f32 -> [B][1024][256] bf16 ----------------
__global__ void k_f2t(const float* __restrict__ f2, u16* __restrict__ f2t) {
    int b = blockIdx.z, ct = blockIdx.y, gt = blockIdx.x;
    __shared__ u16 tile[64][65];
    int t = threadIdx.x; int g = t & 63; int q = t >> 6;
    for (int p = 0; p < 16; ++p) {
        int cl = p * 4 + q;
        tile[g][cl] = f2bf(f2[((size_t)(b * D2 + ct * 64 + cl)) * GG + gt * 64 + g]);
    }
    __syncthreads();
    for (int p = 0; p < 16; ++p) {
        int gl = p * 4 + q;
        f2t[((size_t)(b * GG + gt * 64 + gl)) * D2 + ct * 64 + g] = tile[gl][g];
    }
}

// ---------------- 3-NN (fp32 scan, top-4, fp64 refine) + inverse-distance weights ----------------
__global__ void k_knn(const float* __restrict__ c1, const float* __restrict__ c2,
                      int* __restrict__ idxo, float* __restrict__ wo) {
    int b = blockIdx.y; int t = threadIdx.x;
    int n = blockIdx.x * 256 + t;
    __shared__ float sx[GG], sy[GG], sz[GG], sn[GG];
    const float* cb = c2 + (size_t)b * 3 * GG;
    for (int i = t; i < GG; i += 256) {
        float x = cb[i], y = cb[GG + i], z = cb[2 * GG + i];
        sx[i] = x; sy[i] = y; sz[i] = z; sn[i] = x * x + y * y + z * z;
    }
    __syncthreads();
    const float* pb = c1 + (size_t)b * 3 * NN;
    float px = pb[n], py = pb[NN + n], pz = pb[2 * NN + n];
    float pn = px * px + py * py + pz * pz;
    float d0 = 3.4e38f, d1 = 3.4e38f, d2 = 3.4e38f, d3 = 3.4e38f;
    int i0 = 0, i1 = 0, i2 = 0, i3 = 0;
    for (int g = 0; g < GG; ++g) {
        float dot = px * sx[g] + py * sy[g] + pz * sz[g];
        float d = pn + sn[g] - 2.f * dot;
        if (d < d3) {
            if (d < d2) {
                d3 = d2; i3 = i2;
                if (d < d1) {
                    d2 = d1; i2 = i1;
                    if (d < d0) { d1 = d0; i1 = i0; d0 = d; i0 = g; }
                    else { d1 = d; i1 = g; }
                } else { d2 = d; i2 = g; }
            } else { d3 = d; i3 = g; }
        }
    }
    double dd[4]; int id[4] = { i0, i1, i2, i3 };
    #pragma unroll
    for (int k = 0; k < 4; ++k) {
        int g = id[k];
        double dx = (double)px - (double)sx[g];
        double dy = (double)py - (double)sy[g];
        double dz = (double)pz - (double)sz[g];
        dd[k] = dx * dx + dy * dy + dz * dz;
    }
    #pragma unroll
    for (int a = 0; a < 3; ++a) {
        int best = a;
        #pragma unroll
        for (int c = a + 1; c < 4; ++c)
            if (dd[c] < dd[best] || (dd[c] == dd[best] && id[c] < id[best])) best = c;
        double td = dd[a]; dd[a] = dd[best]; dd[best] = td;
        int ti = id[a]; id[a] = id[best]; id[best] = ti;
    }
    float r0 = 1.f / ((float)dd[0] + 1e-8f);
    float r1 = 1.f / ((float)dd[1] + 1e-8f);
    float r2 = 1.f / ((float)dd[2] + 1e-8f);
    float s = r0 + r1 + r2;
    size_t base = ((size_t)b * NN + n) * 3;
    idxo[base] = id[0]; idxo[base + 1] = id[1]; idxo[base + 2] = id[2];
    wo[base] = r0 / s; wo[base + 1] = r1 / s; wo[base + 2] = r2 / s;
}

// ---------------- build X [B*N][384] bf16: cols 0..127 = feature1^T, 128..383 = interp ----------------
__global__ void k_pack(const float* __restrict__ f1, const u16* __restrict__ f2t,
                       const int* __restrict__ idxo, const float* __restrict__ wo,
                       u16* __restrict__ Xp) {
    int b = blockIdx.y; int n0 = blockIdx.x * 64;
    __shared__ u16 Xt[64][392];          // 384 + 8 pad (row stride 784 B = 49*16 -> aligned, conflict-light)
    int t = threadIdx.x; int j = t & 63; int q = t >> 6;
    // feature1 part
    for (int p = 0; p < 4; ++p) {
        int oct = p * 4 + q; int cb = oct * 8;
        u16x8 o;
        #pragma unroll
        for (int k = 0; k < 8; ++k)
            o[k] = f2bf(f1[((size_t)(b * D1 + cb + k)) * NN + n0 + j]);
        *(u16x8*)&Xt[j][cb] = o;
    }
    // interp part
    size_t bn = (size_t)b * NN + n0 + j;
    int g0 = idxo[bn * 3], g1 = idxo[bn * 3 + 1], g2 = idxo[bn * 3 + 2];
    float w0 = wo[bn * 3], w1 = wo[bn * 3 + 1], w2 = wo[bn * 3 + 2];
    const u16* r0 = f2t + ((size_t)b * GG + g0) * D2;
    const u16* r1 = f2t + ((size_t)b * GG + g1) * D2;
    const u16* r2 = f2t + ((size_t)b * GG + g2) * D2;
    for (int p = 0; p < 8; ++p) {
        int oct = p * 4 + q; int cb = oct * 8;
        u16x8 a = *(const u16x8*)(r0 + cb);
        u16x8 bb = *(const u16x8*)(r1 + cb);
        u16x8 cc = *(const u16x8*)(r2 + cb);
        u16x8 o;
        #pragma unroll
        for (int k = 0; k < 8; ++k)
            o[k] = f2bf(w0 * bf2f(a[k]) + w1 * bf2f(bb[k]) + w2 * bf2f(cc[k]));
        *(u16x8*)&Xt[j][D1 + cb] = o;
    }
    __syncthreads();
    // linear copy-out (global side is fully contiguous)
    u16* dst = Xp + ((size_t)b * NN + n0) * CIN;
    for (int p = 0; p < 12; ++p) {
        int ci = p * 256 + t;           // 0..3071 chunks of 8 u16
        int row = ci / 48, ch = ci % 48;
        *(u16x8*)(dst + (size_t)ci * 8) = *(const u16x8*)&Xt[row][ch * 8];
    }
}

// ---------------- GEMM: Y[n][c] (bf16) = A[256][K] * X[n][K]^T + bias ----------------
template<int K>
__global__ __launch_bounds__(256) void k_gemm(const u16* __restrict__ A, const u16* __restrict__ Bm,
                                              const float* __restrict__ bias, u16* __restrict__ Yp) {
    int nt = blockIdx.x, mt = blockIdx.y, b = blockIdx.z;
    int c0 = mt * 128; size_t n0 = (size_t)b * NN + nt * 128;
    __shared__ u16 Al[128 * 32], Bl[128 * 32];
    int t = threadIdx.x, lane = t & 63, w = t >> 6;
    int wr = w >> 1, wc = w & 1;
    f32x4 acc[4][4];
    #pragma unroll
    for (int m = 0; m < 4; ++m)
        #pragma unroll
        for (int n = 0; n < 4; ++n) acc[m][n] = (f32x4){0.f, 0.f, 0.f, 0.f};
    int lr = w * 32 + (lane >> 2);
    int lc = (lane & 3) * 8;
    for (int ks = 0; ks < K / 32; ++ks) {
        __syncthreads();
        #pragma unroll
        for (int i = 0; i < 2; ++i) {
            gload16(A + (size_t)(c0 + lr + i * 16) * K + ks * 32 + lc, Al + (w * 32 + i * 16) * 32);
            gload16(Bm + (n0 + lr + i * 16) * K + ks * 32 + lc, Bl + (w * 32 + i * 16) * 32);
        }
        __syncthreads();
        bf16x8 af[4], bfr[4];
        #pragma unroll
        for (int m = 0; m < 4; ++m)
            af[m] = *(const bf16x8*)&Al[(wr * 64 + m * 16 + (lane & 15)) * 32 + (lane >> 4) * 8];
        #pragma unroll
        for (int n = 0; n < 4; ++n)
            bfr[n] = *(const bf16x8*)&Bl[(wc * 64 + n * 16 + (lane & 15)) * 32 + (lane >> 4) * 8];
        #pragma unroll
        for (int m = 0; m < 4; ++m)
            #pragma unroll
            for (int n = 0; n < 4; ++n)
                acc[m][n] = __builtin_amdgcn_mfma_f32_16x16x32_bf16(af[m], bfr[n], acc[m][n], 0, 0, 0);
    }
    #pragma unroll
    for (int m = 0; m < 4; ++m) {
        int c = c0 + wr * 64 + m * 16 + (lane >> 4) * 4;
        float b0 = bias[c], b1 = bias[c + 1], b2 = bias[c + 2], b3 = bias[c + 3];
        #pragma unroll
        for (int n = 0; n < 4; ++n) {
            size_t nn = n0 + wc * 64 + n * 16 + (lane & 15);
            f32x4 v = acc[m][n];
            u16x4 o;
            o[0] = f2bf(v[0] + b0); o[1] = f2bf(v[1] + b1);
            o[2] = f2bf(v[2] + b2); o[3] = f2bf(v[3] + b3);
            *(u16x4*)(Yp + nn * CH + c) = o;
        }
    }
}

// ---------------- per-channel sum / sumsq over [65536][256] bf16 ----------------
__global__ void k_stats(const u16* __restrict__ Y, float* __restrict__ S1, float* __restrict__ S2) {
    __shared__ float bs[2048], bq[2048];
    int t = threadIdx.x;
    int cg = (t & 31) * 8, rl = t >> 5;
    size_t r0 = (size_t)blockIdx.x * 256;
    float s[8], qq[8];
    #pragma unroll
    for (int k = 0; k < 8; ++k) { s[k] = 0.f; qq[k] = 0.f; }
    for (int r = rl; r < 256; r += 8) {
        u16x8 v = *(const u16x8*)(Y + (r0 + r) * CH + cg);
        #pragma unroll
        for (int k = 0; k < 8; ++k) { float f = bf2f(v[k]); s[k] += f; qq[k] += f * f; }
    }
    #pragma unroll
    for (int k = 0; k < 8; ++k) { bs[t * 8 + k] = s[k]; bq[t * 8 + k] = qq[k]; }
    __syncthreads();
    if (t < 32) {
        float a[8], c[8];
        #pragma unroll
        for (int k = 0; k < 8; ++k) { a[k] = 0.f; c[k] = 0.f; }
        for (int rr = 0; rr < 8; ++rr) {
            int tt = rr * 32 + t;
            #pragma unroll
            for (int k = 0; k < 8; ++k) { a[k] += bs[tt * 8 + k]; c[k] += bq[tt * 8 + k]; }
        }
        #pragma unroll
        for (int k = 0; k < 8; ++k) {
            atomicAdd(&S1[t * 8 + k], a[k]);
            atomicAdd(&S2[t * 8 + k], c[k]);
        }
    }
}

// ---------------- finalize BN scale/shift ----------------
__global__ void k_fin(const float* __restrict__ S1, const float* __restrict__ S2,
                      const float* __restrict__ gamma, const float* __restrict__ beta,
                      float* __restrict__ scale, float* __restrict__ shift) {
    int c = threadIdx.x;
    float inv = 1.f / 65536.f;
    float m = S1[c] * inv;
    float v = S2[c] * inv - m * m;
    float sc = gamma[c] * rsqrtf(v + 1e-5f);
    scale[c] = sc; shift[c] = beta[c] - m * sc;
}

// ---------------- normalize + relu (bf16 -> bf16) ----------------
__global__ void k_bnrelu(const u16* __restrict__ Y, const float* __restrict__ scale,
                         const float* __restrict__ shift, u16* __restrict__ X2) {
    __shared__ float sc[256], sh[256];
    int t = threadIdx.x;
    sc[t] = scale[t]; sh[t] = shift[t];
    __syncthreads();
    size_t i = ((size_t)blockIdx.x * 256 + t) * 8;
    int c = (int)(i & 255);
    u16x8 v = *(const u16x8*)(Y + i);
    u16x8 o;
    #pragma unroll
    for (int k = 0; k < 8; ++k) {
        float f = fmaxf(sc[c + k] * bf2f(v[k]) + sh[c + k], 0.f);
        o[k] = f2bf(f);
    }
    *(u16x8*)(X2 + i) = o;
}

// ---------------- final: normalize + relu + transpose to [B][256][N] f32 ----------------
__global__ void k_final(const u16* __restrict__ Y2, const float* __restrict__ scale,
                        const float* __restrict__ shift, float* __restrict__ out) {
    int b = blockIdx.y, n0 = blockIdx.x * 64;
    __shared__ u16 tile[64 * 256];
    __shared__ float sc[256], sh[256];
    int t = threadIdx.x;
    sc[t] = scale[t]; sh[t] = shift[t];
    #pragma unroll
    for (int p = 0; p < 8; ++p) {
        int r = p * 8 + (t >> 5); int o = t & 31;
        u16x8 v = *(const u16x8*)(Y2 + ((size_t)(b * NN + n0 + r)) * CH + o * 8);
        int osw = o ^ (r & 7);                       // oct-XOR swizzle (keeps 16B alignment)
        *(u16x8*)&tile[r * 256 + osw * 8] = v;
    }
    __syncthreads();
    for (int p = 0; p < 64; ++p) {
        int c = p * 4 + (t >> 6); int n = t & 63;
        int osw = (c >> 3) ^ (n & 7);
        float f = bf2f(tile[n * 256 + osw * 8 + (c & 7)]);
        out[((size_t)(b * CH + c)) * NN + n0 + n] = fmaxf(sc[c] * f + sh[c], 0.f);
    }
}

extern "C" void kernel_launch(void* const* d_in, const int* in_sizes, int n_in,
                              void* d_out, int out_size, void* d_ws, size_t ws_size,
                              hipStream_t stream) {
    const float* f1  = (const float*)d_in[0];
    const float* c1  = (const float*)d_in[1];
    const float* f2  = (const float*)d_in[2];
    const float* c2  = (const float*)d_in[3];
    const float* W1  = (const float*)d_in[4];
    const float* b1  = (const float*)d_in[5];
    const float* g1  = (const float*)d_in[6];
    const float* be1 = (const float*)d_in[7];
    const float* W2  = (const float*)d_in[8];
    const float* b2  = (const float*)d_in[9];
    const float* g2  = (const float*)d_in[10];
    const float* be2 = (const float*)d_in[11];
    float* out = (float*)d_out;
    char* ws = (char*)d_ws;

    u16* Xp    = (u16*)(ws);                    // [65536][384] bf16 = 50,331,648 B
    u16* Y1p   = (u16*)(ws + 50331648);         // [65536][256] bf16 = 33,554,432 B
    u16* X2p   = Xp;                            // reuse (Xp dead after GEMM1)
    u16* Y2p   = Y1p;                           // reuse (Y1p dead after bnrelu)
    u16* W1b   = (u16*)(ws + 83886080);         // 196,608 B
    u16* W2b   = (u16*)(ws + 84082688);         // 131,072 B
    u16* F2t   = (u16*)(ws + 84213760);         // 8,388,608 B
    int*  idxo = (int*)(ws + 92602368);         // 786,432 B
    float* wo  = (float*)(ws + 93388800);       // 786,432 B
    float* stats = (float*)(ws + 94175232);     // 8,192 B
    float* S1a = stats,        *S2a = stats + 256;
    float* S1b = stats + 512,  *S2b = stats + 768;
    float* sc1 = stats + 1024, *sh1 = stats + 1280;
    float* sc2 = stats + 1536, *sh2 = stats + 1792;

    hipMemsetAsync(stats, 0, 4096, stream);
    k_convw<<<640, 256, 0, stream>>>(W1, W2, W1b, W2b);
    k_f2t<<<dim3(16, 4, 16), 256, 0, stream>>>(f2, F2t);
    k_knn<<<dim3(16, 16), 256, 0, stream>>>(c1, c2, idxo, wo);
    k_pack<<<dim3(64, 16), 256, 0, stream>>>(f1, F2t, idxo, wo, Xp);
    k_gemm<CIN><<<dim3(32, 2, 16), 256, 0, stream>>>(W1b, Xp, b1, Y1p);
    k_stats<<<256, 256, 0, stream>>>(Y1p, S1a, S2a);
    k_fin<<<1, 256, 0, stream>>>(S1a, S2a, g1, be1, sc1, sh1);
    k_bnrelu<<<8192, 256, 0, stream>>>(Y1p, sc1, sh1, X2p);
    k_gemm<CH><<<dim3(32, 2, 16), 256, 0, stream>>>(W2b, X2p, b2, Y2p);
    k_stats<<<256, 256, 0, stream>>>(Y2p, S1b, S2b);
    k_fin<<<1, 256, 0, stream>>>(S1b, S2b, g2, be2, sc2, sh2);
    k_final<<<dim3(64, 16), 256, 0, stream>>>(Y2p, sc2, sh2, out);
}

// Round 2
// 394.803 us; speedup vs baseline: 1.1815x; 1.1815x over previous
//
#include <hip/hip_runtime.h>

#define DEVI __device__ __forceinline__

typedef unsigned short u16;
typedef unsigned int   u32;
typedef u16  u16x8 __attribute__((ext_vector_type(8)));
typedef u16  u16x4 __attribute__((ext_vector_type(4)));
typedef short bf16x8 __attribute__((ext_vector_type(8)));
typedef float f32x4 __attribute__((ext_vector_type(4)));

static constexpr int BB = 16, NN = 4096, GG = 1024;
static constexpr int D1 = 128, D2 = 256, CIN = 384, CH = 256;

DEVI float bf2f(u16 h) { u32 u = ((u32)h) << 16; float f; __builtin_memcpy(&f, &u, 4); return f; }
DEVI u16 f2bf(float f) {
    u32 u; __builtin_memcpy(&u, &f, 4);
    u32 r = (u + 0x7fffu + ((u >> 16) & 1u)) >> 16;
    return (u16)r;
}

DEVI void gload16(const void* g, void* l) {
    __builtin_amdgcn_global_load_lds((const __attribute__((address_space(1))) void*)g,
                                     (__attribute__((address_space(3))) void*)l, 16, 0, 0);
}

// ---------------- weight conversion fp32 -> bf16 ----------------
__global__ void k_convw(const float* __restrict__ W1, const float* __restrict__ W2,
                        u16* __restrict__ W1b, u16* __restrict__ W2b) {
    int i = blockIdx.x * 256 + threadIdx.x;
    if (i < CH * CIN) W1b[i] = f2bf(W1[i]);
    int j = i - CH * CIN;
    if (j >= 0 && j < CH * CH) W2b[j] = f2bf(W2[j]);
}

// ---------------- feature2 transpose: [B][256][1024] f32 -> [B][1024][256] bf16 ----------------
__global__ void k_f2t(const float* __restrict__ f2, u16* __restrict__ f2t) {
    int b = blockIdx.z, ct = blockIdx.y, gt = blockIdx.x;
    __shared__ u16 tile[64][65];
    int t = threadIdx.x; int g = t & 63; int q = t >> 6;
    for (int p = 0; p < 16; ++p) {
        int cl = p * 4 + q;
        tile[g][cl] = f2bf(f2[((size_t)(b * D2 + ct * 64 + cl)) * GG + gt * 64 + g]);
    }
    __syncthreads();
    for (int p = 0; p < 16; ++p) {
        int gl = p * 4 + q;
        f2t[((size_t)(b * GG + gt * 64 + gl)) * D2 + ct * 64 + g] = tile[gl][g];
    }
}

// ---------------- 3-NN: 4 threads/query, fp32 scan (float4 LDS), fp64 re-rank of 16 ----------------
__global__ __launch_bounds__(256) void k_knn(const float* __restrict__ c1, const float* __restrict__ c2,
                                             int* __restrict__ idxo, float* __restrict__ wo) {
    int b = blockIdx.y; int t = threadIdx.x;
    int q = t >> 2, s = t & 3;
    int n = blockIdx.x * 64 + q;
    __shared__ float4 sp[GG];
    __shared__ int mi[256][4];
    const float* cb = c2 + (size_t)b * 3 * GG;
    for (int i = t; i < GG; i += 256) {
        float x = cb[i], y = cb[GG + i], z = cb[2 * GG + i];
        sp[i] = make_float4(x, y, z, x * x + y * y + z * z);
    }
    __syncthreads();
    const float* pb = c1 + (size_t)b * 3 * NN;
    float px = pb[n], py = pb[NN + n], pz = pb[2 * NN + n];
    float pn = px * px + py * py + pz * pz;
    float d0 = 3.4e38f, d1 = 3.4e38f, d2 = 3.4e38f, d3 = 3.4e38f;
    int i0 = 0, i1 = 0, i2 = 0, i3 = 0;
    for (int gb = 0; gb < GG; gb += 16) {
        #pragma unroll
        for (int u = 0; u < 4; ++u) {
            int g = gb + u * 4 + s;
            float4 p = sp[g];
            float d = pn + p.w - 2.f * (px * p.x + py * p.y + pz * p.z);
            if (d < d3) {
                if (d < d2) {
                    d3 = d2; i3 = i2;
                    if (d < d1) {
                        d2 = d1; i2 = i1;
                        if (d < d0) { d1 = d0; i1 = i0; d0 = d; i0 = g; }
                        else { d1 = d; i1 = g; }
                    } else { d2 = d; i2 = g; }
                } else { d3 = d; i3 = g; }
            }
        }
    }
    mi[t][0] = i0; mi[t][1] = i1; mi[t][2] = i2; mi[t][3] = i3;
    __syncthreads();
    if (s == 0) {
        // lexicographic (dist, idx) streaming top-3 over the 16 candidates, fp64
        double e0 = 1e300, e1 = 1e300, e2 = 1e300;
        int j0 = 0x7fffffff, j1 = 0x7fffffff, j2 = 0x7fffffff;
        #pragma unroll 4
        for (int k = 0; k < 16; ++k) {
            int g = mi[q * 4 + (k >> 2)][k & 3];
            float4 p = sp[g];
            double dx = (double)px - (double)p.x;
            double dy = (double)py - (double)p.y;
            double dz = (double)pz - (double)p.z;
            double d = dx * dx + dy * dy + dz * dz;
            bool lt2 = d < e2 || (d == e2 && g < j2);
            if (lt2) {
                bool lt1 = d < e1 || (d == e1 && g < j1);
                if (lt1) {
                    e2 = e1; j2 = j1;
                    bool lt0 = d < e0 || (d == e0 && g < j0);
                    if (lt0) { e1 = e0; j1 = j0; e0 = d; j0 = g; }
                    else { e1 = d; j1 = g; }
                } else { e2 = d; j2 = g; }
            }
        }
        float r0 = 1.f / ((float)e0 + 1e-8f);
        float r1 = 1.f / ((float)e1 + 1e-8f);
        float r2 = 1.f / ((float)e2 + 1e-8f);
        float sum = r0 + r1 + r2;
        size_t base = ((size_t)b * NN + n) * 3;
        idxo[base] = j0; idxo[base + 1] = j1; idxo[base + 2] = j2;
        wo[base] = r0 / sum; wo[base + 1] = r1 / sum; wo[base + 2] = r2 / sum;
    }
}

// ---------------- build X [B*N][384] bf16: cols 0..127 = feature1^T, 128..383 = interp ----------------
__global__ void k_pack(const float* __restrict__ f1, const u16* __restrict__ f2t,
                       const int* __restrict__ idxo, const float* __restrict__ wo,
                       u16* __restrict__ Xp) {
    int b = blockIdx.y; int n0 = blockIdx.x * 64;
    __shared__ u16 Xt[64][392];          // 384 + 8 pad (row stride 784 B = 49*16 -> aligned, conflict-light)
    int t = threadIdx.x; int j = t & 63; int q = t >> 6;
    // feature1 part
    for (int p = 0; p < 4; ++p) {
        int oct = p * 4 + q; int cb = oct * 8;
        u16x8 o;
        #pragma unroll
        for (int k = 0; k < 8; ++k)
            o[k] = f2bf(f1[((size_t)(b * D1 + cb + k)) * NN + n0 + j]);
        *(u16x8*)&Xt[j][cb] = o;
    }
    // interp part
    size_t bn = (size_t)b * NN + n0 + j;
    int g0 = idxo[bn * 3], g1 = idxo[bn * 3 + 1], g2 = idxo[bn * 3 + 2];
    float w0 = wo[bn * 3], w1 = wo[bn * 3 + 1], w2 = wo[bn * 3 + 2];
    const u16* r0 = f2t + ((size_t)b * GG + g0) * D2;
    const u16* r1 = f2t + ((size_t)b * GG + g1) * D2;
    const u16* r2 = f2t + ((size_t)b * GG + g2) * D2;
    for (int p = 0; p < 8; ++p) {
        int oct = p * 4 + q; int cb = oct * 8;
        u16x8 a = *(const u16x8*)(r0 + cb);
        u16x8 bb = *(const u16x8*)(r1 + cb);
        u16x8 cc = *(const u16x8*)(r2 + cb);
        u16x8 o;
        #pragma unroll
        for (int k = 0; k < 8; ++k)
            o[k] = f2bf(w0 * bf2f(a[k]) + w1 * bf2f(bb[k]) + w2 * bf2f(cc[k]));
        *(u16x8*)&Xt[j][D1 + cb] = o;
    }
    __syncthreads();
    // linear copy-out (global side is fully contiguous)
    u16* dst = Xp + ((size_t)b * NN + n0) * CIN;
    for (int p = 0; p < 12; ++p) {
        int ci = p * 256 + t;           // 0..3071 chunks of 8 u16
        int row = ci / 48, ch = ci % 48;
        *(u16x8*)(dst + (size_t)ci * 8) = *(const u16x8*)&Xt[row][ch * 8];
    }
}

// ---------------- GEMM: Y[n][c] (bf16) = A[256][K] * X[n][K]^T + bias ----------------
template<int K>
__global__ __launch_bounds__(256) void k_gemm(const u16* __restrict__ A, const u16* __restrict__ Bm,
                                              const float* __restrict__ bias, u16* __restrict__ Yp) {
    int nt = blockIdx.x, mt = blockIdx.y, b = blockIdx.z;
    int c0 = mt * 128; size_t n0 = (size_t)b * NN + nt * 128;
    __shared__ u16 Al[128 * 32], Bl[128 * 32];
    int t = threadIdx.x, lane = t & 63, w = t >> 6;
    int wr = w >> 1, wc = w & 1;
    f32x4 acc[4][4];
    #pragma unroll
    for (int m = 0; m < 4; ++m)
        #pragma unroll
        for (int n = 0; n < 4; ++n) acc[m][n] = (f32x4){0.f, 0.f, 0.f, 0.f};
    int lr = w * 32 + (lane >> 2);
    int lc = (lane & 3) * 8;
    for (int ks = 0; ks < K / 32; ++ks) {
        __syncthreads();
        #pragma unroll
        for (int i = 0; i < 2; ++i) {
            gload16(A + (size_t)(c0 + lr + i * 16) * K + ks * 32 + lc, Al + (w * 32 + i * 16) * 32);
            gload16(Bm + (n0 + lr + i * 16) * K + ks * 32 + lc, Bl + (w * 32 + i * 16) * 32);
        }
        __syncthreads();
        bf16x8 af[4], bfr[4];
        #pragma unroll
        for (int m = 0; m < 4; ++m)
            af[m] = *(const bf16x8*)&Al[(wr * 64 + m * 16 + (lane & 15)) * 32 + (lane >> 4) * 8];
        #pragma unroll
        for (int n = 0; n < 4; ++n)
            bfr[n] = *(const bf16x8*)&Bl[(wc * 64 + n * 16 + (lane & 15)) * 32 + (lane >> 4) * 8];
        #pragma unroll
        for (int m = 0; m < 4; ++m)
            #pragma unroll
            for (int n = 0; n < 4; ++n)
                acc[m][n] = __builtin_amdgcn_mfma_f32_16x16x32_bf16(af[m], bfr[n], acc[m][n], 0, 0, 0);
    }
    #pragma unroll
    for (int m = 0; m < 4; ++m) {
        int c = c0 + wr * 64 + m * 16 + (lane >> 4) * 4;
        float b0 = bias[c], b1 = bias[c + 1], b2 = bias[c + 2], b3 = bias[c + 3];
        #pragma unroll
        for (int n = 0; n < 4; ++n) {
            size_t nn = n0 + wc * 64 + n * 16 + (lane & 15);
            f32x4 v = acc[m][n];
            u16x4 o;
            o[0] = f2bf(v[0] + b0); o[1] = f2bf(v[1] + b1);
            o[2] = f2bf(v[2] + b2); o[3] = f2bf(v[3] + b3);
            *(u16x4*)(Yp + nn * CH + c) = o;
        }
    }
}

// ---------------- per-channel sum / sumsq over [65536][256] bf16 ----------------
__global__ void k_stats(const u16* __restrict__ Y, float* __restrict__ S1, float* __restrict__ S2) {
    __shared__ float bs[2048], bq[2048];
    int t = threadIdx.x;
    int cg = (t & 31) * 8, rl = t >> 5;
    size_t r0 = (size_t)blockIdx.x * 256;
    float s[8], qq[8];
    #pragma unroll
    for (int k = 0; k < 8; ++k) { s[k] = 0.f; qq[k] = 0.f; }
    for (int r = rl; r < 256; r += 8) {
        u16x8 v = *(const u16x8*)(Y + (r0 + r) * CH + cg);
        #pragma unroll
        for (int k = 0; k < 8; ++k) { float f = bf2f(v[k]); s[k] += f; qq[k] += f * f; }
    }
    #pragma unroll
    for (int k = 0; k < 8; ++k) { bs[t * 8 + k] = s[k]; bq[t * 8 + k] = qq[k]; }
    __syncthreads();
    if (t < 32) {
        float a[8], c[8];
        #pragma unroll
        for (int k = 0; k < 8; ++k) { a[k] = 0.f; c[k] = 0.f; }
        for (int rr = 0; rr < 8; ++rr) {
            int tt = rr * 32 + t;
            #pragma unroll
            for (int k = 0; k < 8; ++k) { a[k] += bs[tt * 8 + k]; c[k] += bq[tt * 8 + k]; }
        }
        #pragma unroll
        for (int k = 0; k < 8; ++k) {
            atomicAdd(&S1[t * 8 + k], a[k]);
            atomicAdd(&S2[t * 8 + k], c[k]);
        }
    }
}

// ---------------- finalize BN scale/shift ----------------
__global__ void k_fin(const float* __restrict__ S1, const float* __restrict__ S2,
                      const float* __restrict__ gamma, const float* __restrict__ beta,
                      float* __restrict__ scale, float* __restrict__ shift) {
    int c = threadIdx.x;
    float inv = 1.f / 65536.f;
    float m = S1[c] * inv;
    float v = S2[c] * inv - m * m;
    float sc = gamma[c] * rsqrtf(v + 1e-5f);
    scale[c] = sc; shift[c] = beta[c] - m * sc;
}

// ---------------- normalize + relu (bf16 -> bf16) ----------------
__global__ void k_bnrelu(const u16* __restrict__ Y, const float* __restrict__ scale,
                         const float* __restrict__ shift, u16* __restrict__ X2) {
    __shared__ float sc[256], sh[256];
    int t = threadIdx.x;
    sc[t] = scale[t]; sh[t] = shift[t];
    __syncthreads();
    size_t i = ((size_t)blockIdx.x * 256 + t) * 8;
    int c = (int)(i & 255);
    u16x8 v = *(const u16x8*)(Y + i);
    u16x8 o;
    #pragma unroll
    for (int k = 0; k < 8; ++k) {
        float f = fmaxf(sc[c + k] * bf2f(v[k]) + sh[c + k], 0.f);
        o[k] = f2bf(f);
    }
    *(u16x8*)(X2 + i) = o;
}

// ---------------- final: normalize + relu + transpose to [B][256][N] f32 ----------------
__global__ void k_final(const u16* __restrict__ Y2, const float* __restrict__ scale,
                        const float* __restrict__ shift, float* __restrict__ out) {
    int b = blockIdx.y, n0 = blockIdx.x * 64;
    __shared__ u16 tile[64 * 256];
    __shared__ float sc[256], sh[256];
    int t = threadIdx.x;
    sc[t] = scale[t]; sh[t] = shift[t];
    #pragma unroll
    for (int p = 0; p < 8; ++p) {
        int r = p * 8 + (t >> 5); int o = t & 31;
        u16x8 v = *(const u16x8*)(Y2 + ((size_t)(b * NN + n0 + r)) * CH + o * 8);
        int osw = o ^ (r & 7);                       // oct-XOR swizzle (keeps 16B alignment)
        *(u16x8*)&tile[r * 256 + osw * 8] = v;
    }
    __syncthreads();
    for (int p = 0; p < 64; ++p) {
        int c = p * 4 + (t >> 6); int n = t & 63;
        int osw = (c >> 3) ^ (n & 7);
        float f = bf2f(tile[n * 256 + osw * 8 + (c & 7)]);
        out[((size_t)(b * CH + c)) * NN + n0 + n] = fmaxf(sc[c] * f + sh[c], 0.f);
    }
}

extern "C" void kernel_launch(void* const* d_in, const int* in_sizes, int n_in,
                              void* d_out, int out_size, void* d_ws, size_t ws_size,
                              hipStream_t stream) {
    const float* f1  = (const float*)d_in[0];
    const float* c1  = (const float*)d_in[1];
    const float* f2  = (const float*)d_in[2];
    const float* c2  = (const float*)d_in[3];
    const float* W1  = (const float*)d_in[4];
    const float* b1  = (const float*)d_in[5];
    const float* g1  = (const float*)d_in[6];
    const float* be1 = (const float*)d_in[7];
    const float* W2  = (const float*)d_in[8];
    const float* b2  = (const float*)d_in[9];
    const float* g2  = (const float*)d_in[10];
    const float* be2 = (const float*)d_in[11];
    float* out = (float*)d_out;
    char* ws = (char*)d_ws;

    u16* Xp    = (u16*)(ws);                    // [65536][384] bf16 = 50,331,648 B
    u16* Y1p   = (u16*)(ws + 50331648);         // [65536][256] bf16 = 33,554,432 B
    u16* X2p   = Xp;                            // reuse (Xp dead after GEMM1)
    u16* Y2p   = Y1p;                           // reuse (Y1p dead after bnrelu)
    u16* W1b   = (u16*)(ws + 83886080);         // 196,608 B
    u16* W2b   = (u16*)(ws + 84082688);         // 131,072 B
    u16* F2t   = (u16*)(ws + 84213760);         // 8,388,608 B
    int*  idxo = (int*)(ws + 92602368);         // 786,432 B
    float* wo  = (float*)(ws + 93388800);       // 786,432 B
    float* stats = (float*)(ws + 94175232);     // 8,192 B
    float* S1a = stats,        *S2a = stats + 256;
    float* S1b = stats + 512,  *S2b = stats + 768;
    float* sc1 = stats + 1024, *sh1 = stats + 1280;
    float* sc2 = stats + 1536, *sh2 = stats + 1792;

    hipMemsetAsync(stats, 0, 4096, stream);
    k_convw<<<640, 256, 0, stream>>>(W1, W2, W1b, W2b);
    k_f2t<<<dim3(16, 4, 16), 256, 0, stream>>>(f2, F2t);
    k_knn<<<dim3(64, 16), 256, 0, stream>>>(c1, c2, idxo, wo);
    k_pack<<<dim3(64, 16), 256, 0, stream>>>(f1, F2t, idxo, wo, Xp);
    k_gemm<CIN><<<dim3(32, 2, 16), 256, 0, stream>>>(W1b, Xp, b1, Y1p);
    k_stats<<<256, 256, 0, stream>>>(Y1p, S1a, S2a);
    k_fin<<<1, 256, 0, stream>>>(S1a, S2a, g1, be1, sc1, sh1);
    k_bnrelu<<<8192, 256, 0, stream>>>(Y1p, sc1, sh1, X2p);
    k_gemm<CH><<<dim3(32, 2, 16), 256, 0, stream>>>(W2b, X2p, b2, Y2p);
    k_stats<<<256, 256, 0, stream>>>(Y2p, S1b, S2b);
    k_fin<<<1, 256, 0, stream>>>(S1b, S2b, g2, be2, sc2, sh2);
    k_final<<<dim3(64, 16), 256, 0, stream>>>(Y2p, sc2, sh2, out);
}

// Round 4
// 286.999 us; speedup vs baseline: 1.6252x; 1.3756x over previous
//
#include <hip/hip_runtime.h>

#define DEVI __device__ __forceinline__

typedef unsigned short u16;
typedef unsigned int   u32;
typedef u16  u16x8 __attribute__((ext_vector_type(8)));
typedef u16  u16x4 __attribute__((ext_vector_type(4)));
typedef short bf16x8 __attribute__((ext_vector_type(8)));
typedef float f32x4 __attribute__((ext_vector_type(4)));

static constexpr int BB = 16, NN = 4096, GG = 1024;
static constexpr int D1 = 128, D2 = 256, CIN = 384, CH = 256;

DEVI float bf2f(u16 h) { u32 u = ((u32)h) << 16; float f; __builtin_memcpy(&f, &u, 4); return f; }
DEVI u16 f2bf(float f) {
    u32 u; __builtin_memcpy(&u, &f, 4);
    u32 r = (u + 0x7fffu + ((u >> 16) & 1u)) >> 16;
    return (u16)r;
}

DEVI void gload16(const void* g, void* l) {
    __builtin_amdgcn_global_load_lds((const __attribute__((address_space(1))) void*)g,
                                     (__attribute__((address_space(3))) void*)l, 16, 0, 0);
}

// ---------------- weight conversion fp32 -> bf16 ----------------
__global__ void k_convw(const float* __restrict__ W1, const float* __restrict__ W2,
                        u16* __restrict__ W1b, u16* __restrict__ W2b) {
    int i = blockIdx.x * 256 + threadIdx.x;
    if (i < CH * CIN) W1b[i] = f2bf(W1[i]);
    int j = i - CH * CIN;
    if (j >= 0 && j < CH * CH) W2b[j] = f2bf(W2[j]);
}

// ---------------- feature2 transpose: [B][256][1024] f32 -> [B][1024][256] bf16 ----------------
__global__ void k_f2t(const float* __restrict__ f2, u16* __restrict__ f2t) {
    int b = blockIdx.z, ct = blockIdx.y, gt = blockIdx.x;
    __shared__ u16 tile[64][65];
    int t = threadIdx.x; int g = t & 63; int q = t >> 6;
    for (int p = 0; p < 16; ++p) {
        int cl = p * 4 + q;
        tile[g][cl] = f2bf(f2[((size_t)(b * D2 + ct * 64 + cl)) * GG + gt * 64 + g]);
    }
    __syncthreads();
    for (int p = 0; p < 16; ++p) {
        int gl = p * 4 + q;
        f2t[((size_t)(b * GG + gt * 64 + gl)) * D2 + ct * 64 + g] = tile[gl][g];
    }
}

// ---------------- 3-NN: 4 threads/query, fp32 scan (float4 LDS), fp64 re-rank of 16 ----------------
__global__ __launch_bounds__(256) void k_knn(const float* __restrict__ c1, const float* __restrict__ c2,
                                             int* __restrict__ idxo, float* __restrict__ wo) {
    int b = blockIdx.y; int t = threadIdx.x;
    int q = t >> 2, s = t & 3;
    int n = blockIdx.x * 64 + q;
    __shared__ float4 sp[GG];
    __shared__ int mi[256][4];
    const float* cb = c2 + (size_t)b * 3 * GG;
    for (int i = t; i < GG; i += 256) {
        float x = cb[i], y = cb[GG + i], z = cb[2 * GG + i];
        sp[i] = make_float4(x, y, z, x * x + y * y + z * z);
    }
    __syncthreads();
    const float* pb = c1 + (size_t)b * 3 * NN;
    float px = pb[n], py = pb[NN + n], pz = pb[2 * NN + n];
    float pn = px * px + py * py + pz * pz;
    float d0 = 3.4e38f, d1 = 3.4e38f, d2 = 3.4e38f, d3 = 3.4e38f;
    int i0 = 0, i1 = 0, i2 = 0, i3 = 0;
    for (int gb = 0; gb < GG; gb += 16) {
        #pragma unroll
        for (int u = 0; u < 4; ++u) {
            int g = gb + u * 4 + s;
            float4 p = sp[g];
            float d = pn + p.w - 2.f * (px * p.x + py * p.y + pz * p.z);
            if (d < d3) {
                if (d < d2) {
                    d3 = d2; i3 = i2;
                    if (d < d1) {
                        d2 = d1; i2 = i1;
                        if (d < d0) { d1 = d0; i1 = i0; d0 = d; i0 = g; }
                        else { d1 = d; i1 = g; }
                    } else { d2 = d; i2 = g; }
                } else { d3 = d; i3 = g; }
            }
        }
    }
    mi[t][0] = i0; mi[t][1] = i1; mi[t][2] = i2; mi[t][3] = i3;
    __syncthreads();
    if (s == 0) {
        // lexicographic (dist, idx) streaming top-3 over the 16 candidates, fp64
        double e0 = 1e300, e1 = 1e300, e2 = 1e300;
        int j0 = 0x7fffffff, j1 = 0x7fffffff, j2 = 0x7fffffff;
        #pragma unroll 4
        for (int k = 0; k < 16; ++k) {
            int g = mi[q * 4 + (k >> 2)][k & 3];
            float4 p = sp[g];
            double dx = (double)px - (double)p.x;
            double dy = (double)py - (double)p.y;
            double dz = (double)pz - (double)p.z;
            double d = dx * dx + dy * dy + dz * dz;
            bool lt2 = d < e2 || (d == e2 && g < j2);
            if (lt2) {
                bool lt1 = d < e1 || (d == e1 && g < j1);
                if (lt1) {
                    e2 = e1; j2 = j1;
                    bool lt0 = d < e0 || (d == e0 && g < j0);
                    if (lt0) { e1 = e0; j1 = j0; e0 = d; j0 = g; }
                    else { e1 = d; j1 = g; }
                } else { e2 = d; j2 = g; }
            }
        }
        float r0 = 1.f / ((float)e0 + 1e-8f);
        float r1 = 1.f / ((float)e1 + 1e-8f);
        float r2 = 1.f / ((float)e2 + 1e-8f);
        float sum = r0 + r1 + r2;
        size_t base = ((size_t)b * NN + n) * 3;
        idxo[base] = j0; idxo[base + 1] = j1; idxo[base + 2] = j2;
        wo[base] = r0 / sum; wo[base + 1] = r1 / sum; wo[base + 2] = r2 / sum;
    }
}

// ---------------- build X [B*N][384] bf16: cols 0..127 = feature1^T, 128..383 = interp ----------------
__global__ void k_pack(const float* __restrict__ f1, const u16* __restrict__ f2t,
                       const int* __restrict__ idxo, const float* __restrict__ wo,
                       u16* __restrict__ Xp) {
    int b = blockIdx.y; int n0 = blockIdx.x * 64;
    __shared__ u16 Xt[64][392];          // 384 + 8 pad (row stride 784 B = 49*16 -> aligned, conflict-light)
    int t = threadIdx.x; int j = t & 63; int q = t >> 6;
    // feature1 part
    for (int p = 0; p < 4; ++p) {
        int oct = p * 4 + q; int cb = oct * 8;
        u16x8 o;
        #pragma unroll
        for (int k = 0; k < 8; ++k)
            o[k] = f2bf(f1[((size_t)(b * D1 + cb + k)) * NN + n0 + j]);
        *(u16x8*)&Xt[j][cb] = o;
    }
    // interp part
    size_t bn = (size_t)b * NN + n0 + j;
    int g0 = idxo[bn * 3], g1 = idxo[bn * 3 + 1], g2 = idxo[bn * 3 + 2];
    float w0 = wo[bn * 3], w1 = wo[bn * 3 + 1], w2 = wo[bn * 3 + 2];
    const u16* r0 = f2t + ((size_t)b * GG + g0) * D2;
    const u16* r1 = f2t + ((size_t)b * GG + g1) * D2;
    const u16* r2 = f2t + ((size_t)b * GG + g2) * D2;
    for (int p = 0; p < 8; ++p) {
        int oct = p * 4 + q; int cb = oct * 8;
        u16x8 a = *(const u16x8*)(r0 + cb);
        u16x8 bb = *(const u16x8*)(r1 + cb);
        u16x8 cc = *(const u16x8*)(r2 + cb);
        u16x8 o;
        #pragma unroll
        for (int k = 0; k < 8; ++k)
            o[k] = f2bf(w0 * bf2f(a[k]) + w1 * bf2f(bb[k]) + w2 * bf2f(cc[k]));
        *(u16x8*)&Xt[j][D1 + cb] = o;
    }
    __syncthreads();
    // linear copy-out (global side is fully contiguous)
    u16* dst = Xp + ((size_t)b * NN + n0) * CIN;
    for (int p = 0; p < 12; ++p) {
        int ci = p * 256 + t;           // 0..3071 chunks of 8 u16
        int row = ci / 48, ch = ci % 48;
        *(u16x8*)(dst + (size_t)ci * 8) = *(const u16x8*)&Xt[row][ch * 8];
    }
}

// ---------------- GEMM: Y[n][c] (bf16) = A[256][K] * X[n][K]^T + bias, fused BN stats ----------------
template<int K>
__global__ __launch_bounds__(256) void k_gemm(const u16* __restrict__ A, const u16* __restrict__ Bm,
                                              const float* __restrict__ bias, u16* __restrict__ Yp,
                                              float* __restrict__ S1, float* __restrict__ S2) {
    int nt = blockIdx.x, mt = blockIdx.y, b = blockIdx.z;
    int c0 = mt * 128; size_t n0 = (size_t)b * NN + nt * 128;
    __shared__ u16 Al[128 * 32], Bl[128 * 32];
    __shared__ float sred[4][64], qred[4][64];
    int t = threadIdx.x, lane = t & 63, w = t >> 6;
    int wr = w >> 1, wc = w & 1;
    f32x4 acc[4][4];
    #pragma unroll
    for (int m = 0; m < 4; ++m)
        #pragma unroll
        for (int n = 0; n < 4; ++n) acc[m][n] = (f32x4){0.f, 0.f, 0.f, 0.f};
    int lr = w * 32 + (lane >> 2);
    int lc = (lane & 3) * 8;
    for (int ks = 0; ks < K / 32; ++ks) {
        __syncthreads();
        #pragma unroll
        for (int i = 0; i < 2; ++i) {
            gload16(A + (size_t)(c0 + lr + i * 16) * K + ks * 32 + lc, Al + (w * 32 + i * 16) * 32);
            gload16(Bm + (n0 + lr + i * 16) * K + ks * 32 + lc, Bl + (w * 32 + i * 16) * 32);
        }
        __syncthreads();
        bf16x8 af[4], bfr[4];
        #pragma unroll
        for (int m = 0; m < 4; ++m)
            af[m] = *(const bf16x8*)&Al[(wr * 64 + m * 16 + (lane & 15)) * 32 + (lane >> 4) * 8];
        #pragma unroll
        for (int n = 0; n < 4; ++n)
            bfr[n] = *(const bf16x8*)&Bl[(wc * 64 + n * 16 + (lane & 15)) * 32 + (lane >> 4) * 8];
        #pragma unroll
        for (int m = 0; m < 4; ++m)
            #pragma unroll
            for (int n = 0; n < 4; ++n)
                acc[m][n] = __builtin_amdgcn_mfma_f32_16x16x32_bf16(af[m], bfr[n], acc[m][n], 0, 0, 0);
    }
    // epilogue: bias + bf16 store + per-channel partial sums (y and y^2) over this block's 128 cols
    float sacc[4][4], qacc[4][4];
    #pragma unroll
    for (int m = 0; m < 4; ++m) {
        int c = c0 + wr * 64 + m * 16 + (lane >> 4) * 4;
        float b0 = bias[c], b1 = bias[c + 1], b2 = bias[c + 2], b3 = bias[c + 3];
        #pragma unroll
        for (int j = 0; j < 4; ++j) { sacc[m][j] = 0.f; qacc[m][j] = 0.f; }
        #pragma unroll
        for (int n = 0; n < 4; ++n) {
            size_t nn = n0 + wc * 64 + n * 16 + (lane & 15);
            f32x4 v = acc[m][n];
            float y0 = v[0] + b0, y1 = v[1] + b1, y2 = v[2] + b2, y3 = v[3] + b3;
            u16x4 o;
            o[0] = f2bf(y0); o[1] = f2bf(y1); o[2] = f2bf(y2); o[3] = f2bf(y3);
            *(u16x4*)(Yp + nn * CH + c) = o;
            sacc[m][0] += y0; qacc[m][0] += y0 * y0;
            sacc[m][1] += y1; qacc[m][1] += y1 * y1;
            sacc[m][2] += y2; qacc[m][2] += y2 * y2;
            sacc[m][3] += y3; qacc[m][3] += y3 * y3;
        }
    }
    // reduce across the 16 lane-columns (bits 0..3 of lane; bits 4..5 = channel group)
    #pragma unroll
    for (int m = 0; m < 4; ++m)
        #pragma unroll
        for (int j = 0; j < 4; ++j) {
            float s = sacc[m][j], qv = qacc[m][j];
            #pragma unroll
            for (int mask = 1; mask <= 8; mask <<= 1) {
                s  += __shfl_xor(s, mask);
                qv += __shfl_xor(qv, mask);
            }
            sacc[m][j] = s; qacc[m][j] = qv;
        }
    int g = lane >> 4;
    if ((lane & 15) == 0) {
        #pragma unroll
        for (int m = 0; m < 4; ++m)
            #pragma unroll
            for (int j = 0; j < 4; ++j) {
                sred[w][m * 16 + g * 4 + j] = sacc[m][j];
                qred[w][m * 16 + g * 4 + j] = qacc[m][j];
            }
    }
    __syncthreads();
    if (t < 128) {
        int half = t >> 6, cl = t & 63;
        float s  = sred[half * 2][cl] + sred[half * 2 + 1][cl];
        float qv = qred[half * 2][cl] + qred[half * 2 + 1][cl];
        atomicAdd(&S1[c0 + half * 64 + cl], s);
        atomicAdd(&S2[c0 + half * 64 + cl], qv);
    }
}

// ---------------- finalize BN scale/shift ----------------
__global__ void k_fin(const float* __restrict__ S1, const float* __restrict__ S2,
                      const float* __restrict__ gamma, const float* __restrict__ beta,
                      float* __restrict__ scale, float* __restrict__ shift) {
    int c = threadIdx.x;
    float inv = 1.f / 65536.f;
    float m = S1[c] * inv;
    float v = S2[c] * inv - m * m;
    float sc = gamma[c] * rsqrtf(v + 1e-5f);
    scale[c] = sc; shift[c] = beta[c] - m * sc;
}

// ---------------- normalize + relu (bf16 -> bf16) ----------------
__global__ void k_bnrelu(const u16* __restrict__ Y, const float* __restrict__ scale,
                         const float* __restrict__ shift, u16* __restrict__ X2) {
    __shared__ float sc[256], sh[256];
    int t = threadIdx.x;
    sc[t] = scale[t]; sh[t] = shift[t];
    __syncthreads();
    size_t i = ((size_t)blockIdx.x * 256 + t) * 8;
    int c = (int)(i & 255);
    u16x8 v = *(const u16x8*)(Y + i);
    u16x8 o;
    #pragma unroll
    for (int k = 0; k < 8; ++k) {
        float f = fmaxf(sc[c + k] * bf2f(v[k]) + sh[c + k], 0.f);
        o[k] = f2bf(f);
    }
    *(u16x8*)(X2 + i) = o;
}

// ---------------- final: normalize + relu + transpose to [B][256][N] f32 ----------------
__global__ void k_final(const u16* __restrict__ Y2, const float* __restrict__ scale,
                        const float* __restrict__ shift, float* __restrict__ out) {
    int b = blockIdx.y, n0 = blockIdx.x * 64;
    __shared__ u16 tile[64 * 256];
    __shared__ float sc[256], sh[256];
    int t = threadIdx.x;
    sc[t] = scale[t]; sh[t] = shift[t];
    #pragma unroll
    for (int p = 0; p < 8; ++p) {
        int r = p * 8 + (t >> 5); int o = t & 31;
        u16x8 v = *(const u16x8*)(Y2 + ((size_t)(b * NN + n0 + r)) * CH + o * 8);
        int osw = o ^ (r & 7);                       // oct-XOR swizzle (keeps 16B alignment)
        *(u16x8*)&tile[r * 256 + osw * 8] = v;
    }
    __syncthreads();
    for (int p = 0; p < 64; ++p) {
        int c = p * 4 + (t >> 6); int n = t & 63;
        int osw = (c >> 3) ^ (n & 7);
        float f = bf2f(tile[n * 256 + osw * 8 + (c & 7)]);
        out[((size_t)(b * CH + c)) * NN + n0 + n] = fmaxf(sc[c] * f + sh[c], 0.f);
    }
}

extern "C" void kernel_launch(void* const* d_in, const int* in_sizes, int n_in,
                              void* d_out, int out_size, void* d_ws, size_t ws_size,
                              hipStream_t stream) {
    const float* f1  = (const float*)d_in[0];
    const float* c1  = (const float*)d_in[1];
    const float* f2  = (const float*)d_in[2];
    const float* c2  = (const float*)d_in[3];
    const float* W1  = (const float*)d_in[4];
    const float* b1  = (const float*)d_in[5];
    const float* g1  = (const float*)d_in[6];
    const float* be1 = (const float*)d_in[7];
    const float* W2  = (const float*)d_in[8];
    const float* b2  = (const float*)d_in[9];
    const float* g2  = (const float*)d_in[10];
    const float* be2 = (const float*)d_in[11];
    float* out = (float*)d_out;
    char* ws = (char*)d_ws;

    u16* Xp    = (u16*)(ws);                    // [65536][384] bf16 = 50,331,648 B
    u16* Y1p   = (u16*)(ws + 50331648);         // [65536][256] bf16 = 33,554,432 B
    u16* X2p   = Xp;                            // reuse (Xp dead after GEMM1)
    u16* Y2p   = Y1p;                           // reuse (Y1p dead after bnrelu)
    u16* W1b   = (u16*)(ws + 83886080);         // 196,608 B
    u16* W2b   = (u16*)(ws + 84082688);         // 131,072 B
    u16* F2t   = (u16*)(ws + 84213760);         // 8,388,608 B
    int*  idxo = (int*)(ws + 92602368);         // 786,432 B
    float* wo  = (float*)(ws + 93388800);       // 786,432 B
    float* stats = (float*)(ws + 94175232);     // 8,192 B
    float* S1a = stats,        *S2a = stats + 256;
    float* S1b = stats + 512,  *S2b = stats + 768;
    float* sc1 = stats + 1024, *sh1 = stats + 1280;
    float* sc2 = stats + 1536, *sh2 = stats + 1792;

    hipMemsetAsync(stats, 0, 4096, stream);
    k_convw<<<640, 256, 0, stream>>>(W1, W2, W1b, W2b);
    k_f2t<<<dim3(16, 4, 16), 256, 0, stream>>>(f2, F2t);
    k_knn<<<dim3(64, 16), 256, 0, stream>>>(c1, c2, idxo, wo);
    k_pack<<<dim3(64, 16), 256, 0, stream>>>(f1, F2t, idxo, wo, Xp);
    k_gemm<CIN><<<dim3(32, 2, 16), 256, 0, stream>>>(W1b, Xp, b1, Y1p, S1a, S2a);
    k_fin<<<1, 256, 0, stream>>>(S1a, S2a, g1, be1, sc1, sh1);
    k_bnrelu<<<8192, 256, 0, stream>>>(Y1p, sc1, sh1, X2p);
    k_gemm<CH><<<dim3(32, 2, 16), 256, 0, stream>>>(W2b, X2p, b2, Y2p, S1b, S2b);
    k_fin<<<1, 256, 0, stream>>>(S1b, S2b, g2, be2, sc2, sh2);
    k_final<<<dim3(64, 16), 256, 0, stream>>>(Y2p, sc2, sh2, out);
}